// Round 9
// baseline (194.283 us; speedup 1.0000x reference)
//
#include <hip/hip_runtime.h>
#include <hip/hip_bf16.h>
#include <hip/hip_cooperative_groups.h>

namespace cg = cooperative_groups;

// Attention: out[b,q,v] = softmax_d( Q[q,:]·K[b,d,:] / sqrt(128) ) · V[b,d,v]
// B=32, D=8192, DK=DV=128. fp32 in/out, bf16 MFMA internally.
// R8: R4 main loop (proven fastest; R5/R6/R7 proved occupancy & amortization
//     are NOT the limiter — we sit at ~85% of the streaming ceiling). This
//     round removes the remaining structural overhead: combine fused into the
//     same kernel via cooperative launch + grid.sync() (saves launch #2 and
//     the inter-kernel drain; partials stay L2/L3-warm).

#define NSPLIT 16
#define Dseq 8192
#define Dk 128
#define KT 32
#define NT (Dseq / NSPLIT / KT)   // 16 tiles per block

typedef __attribute__((ext_vector_type(8))) short bf16x8;
typedef __attribute__((ext_vector_type(16))) float f32x16;

__device__ __forceinline__ unsigned cvt_pk(float lo, float hi) {
  unsigned d;
  asm("v_cvt_pk_bf16_f32 %0, %1, %2" : "=v"(d) : "v"(lo), "v"(hi));
  return d;
}
__device__ __forceinline__ void plane32_swap(unsigned& a, unsigned& b) {
  // out a = {a.lo, b.lo}, out b = {a.hi, b.hi} across lane<32/lane>=32
  asm volatile("v_permlane32_swap_b32 %0, %1" : "+v"(a), "+v"(b));
}

union frag_u { unsigned u[4]; bf16x8 v; };

// mfma_f32_32x32x16_bf16 layouts (m74/m101 verified):
//  A[32,16]: lane l -> row = l&31, k = (l>>5)*8 + j
//  B[16,32]: lane l -> col = l&31, k = (l>>5)*8 + j
//  C/D     : lane l -> col = l&31, row = (r&3) + 8*(r>>2) + 4*(l>>5)

__global__ __launch_bounds__(256, 2) void attn_fused(
    const float* __restrict__ Q, const float* __restrict__ K,
    const float* __restrict__ V, float* __restrict__ ows,
    float* __restrict__ mws, float* __restrict__ lws,
    float* __restrict__ out) {
  // 16.9 KB: epilogue transpose [128][33]; K bf16 double-buffer (2x8KB)
  // overlays the first 16 KB during the main loop.
  __shared__ alignas(16) float smem[128 * 33];
  char* kls = (char*)smem;

  const int tid = threadIdx.x;
  const int lane = tid & 63;
  const int w = tid >> 6;          // wave 0..3, owns V cols [32w, 32w+32)
  const int c32 = lane & 31;
  const int hi = lane >> 5;
  const int wg = blockIdx.x;
  const int b = wg >> 4;           // NSPLIT=16
  const int kb0 = (wg & 15) * (Dseq / NSPLIT);

  const float scale = 0.088388347648318447f;  // 1/sqrt(128)

  // K staging geometry: wave w owns tile rows [8w, 8w+8); lane covers
  // row 8w+(lane>>3), f32 cols (lane&7)*16 .. +15.
  const int krow_l = 8 * w + (lane >> 3);
  const int kcol0 = (lane & 7) * 16;
  const int ksw = (krow_l & 7) << 4;                  // write-side XOR
  const int ko0 = krow_l * 256 + (lane & 7) * 32;     // tile-local byte

  // ---- Q as B-fragment (q = c32, k = hi*8 + j + 16s), prescaled, resident
  bf16x8 qa[8];
  {
    const float* qrow = Q + c32 * Dk + hi * 8;
#pragma unroll
    for (int s = 0; s < 8; ++s) {
      float4 a = *(const float4*)(qrow + s * 16);
      float4 b4 = *(const float4*)(qrow + s * 16 + 4);
      frag_u f;
      f.u[0] = cvt_pk(a.x * scale, a.y * scale);
      f.u[1] = cvt_pk(a.z * scale, a.w * scale);
      f.u[2] = cvt_pk(b4.x * scale, b4.y * scale);
      f.u[3] = cvt_pk(b4.z * scale, b4.w * scale);
      qa[s] = f.v;
    }
  }

  const float* Kb = K + (size_t)b * Dseq * Dk;
  const float* Vb = V + (size_t)b * Dseq * Dk;

  f32x16 acc;
#pragma unroll
  for (int r = 0; r < 16; ++r) acc[r] = 0.0f;
  float m_r = -1e30f, l_r = 0.0f;

  // ---- prologue: stage K tile 0 into buf 0 (bf16, swizzled)
  {
    const float* src = Kb + (size_t)(kb0 + krow_l) * Dk + kcol0;
    float4 k0 = *(const float4*)(src);
    float4 k1 = *(const float4*)(src + 4);
    float4 k2 = *(const float4*)(src + 8);
    float4 k3 = *(const float4*)(src + 12);
    frag_u lo, hi4;
    lo.u[0] = cvt_pk(k0.x, k0.y);  lo.u[1] = cvt_pk(k0.z, k0.w);
    lo.u[2] = cvt_pk(k1.x, k1.y);  lo.u[3] = cvt_pk(k1.z, k1.w);
    hi4.u[0] = cvt_pk(k2.x, k2.y); hi4.u[1] = cvt_pk(k2.z, k2.w);
    hi4.u[2] = cvt_pk(k3.x, k3.y); hi4.u[3] = cvt_pk(k3.z, k3.w);
    *(bf16x8*)(kls + (ko0 ^ ksw)) = lo.v;
    *(bf16x8*)(kls + ((ko0 + 16) ^ ksw)) = hi4.v;
  }
  __syncthreads();

  for (int t = 0; t < NT; ++t) {
    const int kb = kb0 + t * KT;

    // A) issue V(t) loads (unique per wave: its 32 v-cols x 32 keys, 4KB)
    float vr[16];
    {
      const float* vsrc = Vb + (size_t)(kb + hi * 8) * Dk + 32 * w + c32;
#pragma unroll
      for (int s2 = 0; s2 < 2; ++s2)
#pragma unroll
        for (int j = 0; j < 8; ++j)
          vr[s2 * 8 + j] = vsrc[(size_t)(16 * s2 + j) * Dk];
    }

    // B) issue K(t+1) loads (cooperative: wave's 8 rows, 4KB)
    float4 kr0, kr1, kr2, kr3;
    if (t + 1 < NT) {
      const float* src = Kb + (size_t)(kb + KT + krow_l) * Dk + kcol0;
      kr0 = *(const float4*)(src);
      kr1 = *(const float4*)(src + 4);
      kr2 = *(const float4*)(src + 8);
      kr3 = *(const float4*)(src + 12);
    }
    __builtin_amdgcn_sched_barrier(0);  // keep load issues above compute

    // C) K fragments from LDS buf[t&1] (swizzled b128)
    const char* kbase = kls + (t & 1) * 8192;
    bf16x8 kf[8];
#pragma unroll
    for (int s = 0; s < 8; ++s) {
      const int o = (c32 * 256 + hi * 16 + s * 32) ^ ((c32 & 7) << 4);
      kf[s] = *(const bf16x8*)(kbase + o);
    }

    // D) S^T[key,q] = mfma(A=K, B=Q): lane q=c32, regs = keys crow(r,hi)
    f32x16 S;
#pragma unroll
    for (int r = 0; r < 16; ++r) S[r] = 0.0f;
#pragma unroll
    for (int s = 0; s < 8; ++s)
      S = __builtin_amdgcn_mfma_f32_32x32x16_bf16(kf[s], qa[s], S, 0, 0, 0);

    // E) online softmax, in-register (per-lane q; 16 keys/lane + xhalf)
    float tmax = S[0];
#pragma unroll
    for (int r = 1; r < 16; ++r) tmax = fmaxf(tmax, S[r]);
    tmax = fmaxf(tmax, __shfl_xor(tmax, 32, 64));
    const float mn = fmaxf(m_r, tmax);
    const float sf = __expf(m_r - mn);
    m_r = mn;
    float p[16];
#pragma unroll
    for (int r = 0; r < 16; ++r) p[r] = __expf(S[r] - mn);
    float rs = p[0];
#pragma unroll
    for (int r = 1; r < 16; ++r) rs += p[r];
    rs += __shfl_xor(rs, 32, 64);
    l_r = l_r * sf + rs;
#pragma unroll
    for (int r = 0; r < 16; ++r) acc[r] *= sf;

    // F) P^T -> B-fragments via cvt_pk + permlane32_swap
    unsigned a0 = cvt_pk(p[0], p[1]),   a1 = cvt_pk(p[2], p[3]);
    unsigned a2 = cvt_pk(p[4], p[5]),   a3 = cvt_pk(p[6], p[7]);
    unsigned a4 = cvt_pk(p[8], p[9]),   a5 = cvt_pk(p[10], p[11]);
    unsigned a6 = cvt_pk(p[12], p[13]), a7 = cvt_pk(p[14], p[15]);
    plane32_swap(a0, a2);
    plane32_swap(a1, a3);
    plane32_swap(a4, a6);
    plane32_swap(a5, a7);
    frag_u pa0, pa1;
    pa0.u[0] = a0; pa0.u[1] = a1; pa0.u[2] = a2; pa0.u[3] = a3;
    pa1.u[0] = a4; pa1.u[1] = a5; pa1.u[2] = a6; pa1.u[3] = a7;

    // G) V fragments from the prefetched regs; O^T += mfma(A=V^T, B=P^T)
    frag_u vf0, vf1;
    vf0.u[0] = cvt_pk(vr[0], vr[1]);   vf0.u[1] = cvt_pk(vr[2], vr[3]);
    vf0.u[2] = cvt_pk(vr[4], vr[5]);   vf0.u[3] = cvt_pk(vr[6], vr[7]);
    vf1.u[0] = cvt_pk(vr[8], vr[9]);   vf1.u[1] = cvt_pk(vr[10], vr[11]);
    vf1.u[2] = cvt_pk(vr[12], vr[13]); vf1.u[3] = cvt_pk(vr[14], vr[15]);
    acc = __builtin_amdgcn_mfma_f32_32x32x16_bf16(vf0.v, pa0.v, acc, 0, 0, 0);
    acc = __builtin_amdgcn_mfma_f32_32x32x16_bf16(vf1.v, pa1.v, acc, 0, 0, 0);

    // H) stage K(t+1) into buf[(t+1)&1] (loads had the whole compute window)
    if (t + 1 < NT) {
      frag_u lo, hi4;
      lo.u[0] = cvt_pk(kr0.x, kr0.y);  lo.u[1] = cvt_pk(kr0.z, kr0.w);
      lo.u[2] = cvt_pk(kr1.x, kr1.y);  lo.u[3] = cvt_pk(kr1.z, kr1.w);
      hi4.u[0] = cvt_pk(kr2.x, kr2.y); hi4.u[1] = cvt_pk(kr2.z, kr2.w);
      hi4.u[2] = cvt_pk(kr3.x, kr3.y); hi4.u[3] = cvt_pk(kr3.z, kr3.w);
      char* wbase = kls + ((t + 1) & 1) * 8192;
      *(bf16x8*)(wbase + (ko0 ^ ksw)) = lo.v;
      *(bf16x8*)(wbase + ((ko0 + 16) ^ ksw)) = hi4.v;
    }
    __syncthreads();
  }

  // ---- epilogue: O^T -> smem transpose -> coalesced partial store
  float* ol = smem;  // [128][33]
#pragma unroll
  for (int r = 0; r < 16; ++r) {
    const int vv = 32 * w + (r & 3) + 8 * (r >> 2) + 4 * hi;
    ol[vv * 33 + c32] = acc[r];
  }
  __syncthreads();
  {
    float* oo = ows + (size_t)wg * 4096;
    const int q = tid >> 3;
    const int v0 = (tid & 7) * 16;
#pragma unroll
    for (int g = 0; g < 4; ++g) {
      float4 s;
      s.x = ol[(v0 + 4 * g + 0) * 33 + q];
      s.y = ol[(v0 + 4 * g + 1) * 33 + q];
      s.z = ol[(v0 + 4 * g + 2) * 33 + q];
      s.w = ol[(v0 + 4 * g + 3) * 33 + q];
      *(float4*)(oo + q * 128 + v0 + 4 * g) = s;
    }
  }
  if (w == 0 && hi == 0) {
    mws[wg * 32 + c32] = m_r;
    lws[wg * 32 + c32] = l_r;
  }

  // ---- phase 2: grid-wide sync, then distributed combine (2 bq-rows/block)
  __threadfence();
  cg::this_grid().sync();

  {
    const int bq = 2 * blockIdx.x + (tid >> 7);  // 0..1023
    const int v = tid & 127;
    const int bb = bq >> 5;
    const int qrow = bq & 31;
    const int slot0 = bb * NSPLIT;

    float M = -1e30f;
#pragma unroll
    for (int c = 0; c < NSPLIT; ++c)
      M = fmaxf(M, mws[(slot0 + c) * 32 + qrow]);

    float acc2 = 0.0f, L = 0.0f;
#pragma unroll
    for (int c = 0; c < NSPLIT; ++c) {
      const float f = __expf(mws[(slot0 + c) * 32 + qrow] - M);
      L += lws[(slot0 + c) * 32 + qrow] * f;
      acc2 += f * ows[(size_t)(slot0 + c) * 4096 + qrow * 128 + v];
    }
    out[(size_t)bq * 128 + v] = acc2 / L;
  }
}

extern "C" void kernel_launch(void* const* d_in, const int* in_sizes, int n_in,
                              void* d_out, int out_size, void* d_ws, size_t ws_size,
                              hipStream_t stream) {
  const float* Q = (const float*)d_in[0];
  const float* K = (const float*)d_in[1];
  const float* V = (const float*)d_in[2];
  float* out = (float*)d_out;

  float* ows = (float*)d_ws;                        // 512 * 4096 f32 = 8 MB
  float* mws = ows + (size_t)32 * NSPLIT * 4096;    // 512 * 32 f32
  float* lws = mws + (size_t)32 * NSPLIT * 32;      // 512 * 32 f32

  void* args[] = {(void*)&Q, (void*)&K, (void*)&V,
                  (void*)&ows, (void*)&mws, (void*)&lws, (void*)&out};
  hipLaunchCooperativeKernel((void*)attn_fused, dim3(32 * NSPLIT), dim3(256),
                             args, 0, stream);
}

// Round 11
// 54.836 us; speedup vs baseline: 3.5430x; 3.5430x over previous
//
#include <hip/hip_runtime.h>
#include <hip/hip_bf16.h>

// Attention: out[b,q,v] = softmax_d( Q[q,:]·K[b,d,:] / sqrt(128) ) · V[b,d,v]
// B=32, D=8192, DK=DV=128. fp32 in/out, bf16 MFMA internally.
// R10 = R4 exact (proven best: 55.65 us, passed). Ladder summary:
//   R0 334->R3 pipelined->R4 unique-traffic (55.65) | R5 grid-occ null,
//   R6 amortize null, R7 wave-occ null, R8 grid.sync 3.5x worse, R9 NaN.
// Main loop sits at ~85% of the per-CU streaming ceiling with minimal
// unique traffic; remaining levers exhausted at HIP source level.

#define NSPLIT 16
#define Dseq 8192
#define Dk 128
#define KT 32
#define NT (Dseq / NSPLIT / KT)   // 16 tiles per block

typedef __attribute__((ext_vector_type(8))) short bf16x8;
typedef __attribute__((ext_vector_type(16))) float f32x16;

__device__ __forceinline__ unsigned cvt_pk(float lo, float hi) {
  unsigned d;
  asm("v_cvt_pk_bf16_f32 %0, %1, %2" : "=v"(d) : "v"(lo), "v"(hi));
  return d;
}
__device__ __forceinline__ void plane32_swap(unsigned& a, unsigned& b) {
  // out a = {a.lo, b.lo}, out b = {a.hi, b.hi} across lane<32/lane>=32
  asm volatile("v_permlane32_swap_b32 %0, %1" : "+v"(a), "+v"(b));
}

union frag_u { unsigned u[4]; bf16x8 v; };

// mfma_f32_32x32x16_bf16 layouts (m74/m101 verified):
//  A[32,16]: lane l -> row = l&31, k = (l>>5)*8 + j
//  B[16,32]: lane l -> col = l&31, k = (l>>5)*8 + j
//  C/D     : lane l -> col = l&31, row = (r&3) + 8*(r>>2) + 4*(l>>5)

__global__ __launch_bounds__(256, 2) void attn_partial(
    const float* __restrict__ Q, const float* __restrict__ K,
    const float* __restrict__ V, float* __restrict__ ows,
    float* __restrict__ mws, float* __restrict__ lws) {
  // 16.9 KB: epilogue transpose [128][33]; K bf16 double-buffer (2x8KB)
  // overlays the first 16 KB during the main loop.
  __shared__ alignas(16) float smem[128 * 33];
  char* kls = (char*)smem;

  const int tid = threadIdx.x;
  const int lane = tid & 63;
  const int w = tid >> 6;          // wave 0..3, owns V cols [32w, 32w+32)
  const int c32 = lane & 31;
  const int hi = lane >> 5;
  const int wg = blockIdx.x;
  const int b = wg >> 4;           // NSPLIT=16
  const int kb0 = (wg & 15) * (Dseq / NSPLIT);

  const float scale = 0.088388347648318447f;  // 1/sqrt(128)

  // K staging geometry: wave w owns tile rows [8w, 8w+8); lane covers
  // row 8w+(lane>>3), f32 cols (lane&7)*16 .. +15.
  const int krow_l = 8 * w + (lane >> 3);
  const int kcol0 = (lane & 7) * 16;
  const int ksw = (krow_l & 7) << 4;                  // write-side XOR
  const int ko0 = krow_l * 256 + (lane & 7) * 32;     // tile-local byte

  // ---- Q as B-fragment (q = c32, k = hi*8 + j + 16s), prescaled, resident
  bf16x8 qa[8];
  {
    const float* qrow = Q + c32 * Dk + hi * 8;
#pragma unroll
    for (int s = 0; s < 8; ++s) {
      float4 a = *(const float4*)(qrow + s * 16);
      float4 b4 = *(const float4*)(qrow + s * 16 + 4);
      frag_u f;
      f.u[0] = cvt_pk(a.x * scale, a.y * scale);
      f.u[1] = cvt_pk(a.z * scale, a.w * scale);
      f.u[2] = cvt_pk(b4.x * scale, b4.y * scale);
      f.u[3] = cvt_pk(b4.z * scale, b4.w * scale);
      qa[s] = f.v;
    }
  }

  const float* Kb = K + (size_t)b * Dseq * Dk;
  const float* Vb = V + (size_t)b * Dseq * Dk;

  f32x16 acc;
#pragma unroll
  for (int r = 0; r < 16; ++r) acc[r] = 0.0f;
  float m_r = -1e30f, l_r = 0.0f;

  // ---- prologue: stage K tile 0 into buf 0 (bf16, swizzled)
  {
    const float* src = Kb + (size_t)(kb0 + krow_l) * Dk + kcol0;
    float4 k0 = *(const float4*)(src);
    float4 k1 = *(const float4*)(src + 4);
    float4 k2 = *(const float4*)(src + 8);
    float4 k3 = *(const float4*)(src + 12);
    frag_u lo, hi4;
    lo.u[0] = cvt_pk(k0.x, k0.y);  lo.u[1] = cvt_pk(k0.z, k0.w);
    lo.u[2] = cvt_pk(k1.x, k1.y);  lo.u[3] = cvt_pk(k1.z, k1.w);
    hi4.u[0] = cvt_pk(k2.x, k2.y); hi4.u[1] = cvt_pk(k2.z, k2.w);
    hi4.u[2] = cvt_pk(k3.x, k3.y); hi4.u[3] = cvt_pk(k3.z, k3.w);
    *(bf16x8*)(kls + (ko0 ^ ksw)) = lo.v;
    *(bf16x8*)(kls + ((ko0 + 16) ^ ksw)) = hi4.v;
  }
  __syncthreads();

  for (int t = 0; t < NT; ++t) {
    const int kb = kb0 + t * KT;

    // A) issue V(t) loads (unique per wave: its 32 v-cols x 32 keys, 4KB)
    float vr[16];
    {
      const float* vsrc = Vb + (size_t)(kb + hi * 8) * Dk + 32 * w + c32;
#pragma unroll
      for (int s2 = 0; s2 < 2; ++s2)
#pragma unroll
        for (int j = 0; j < 8; ++j)
          vr[s2 * 8 + j] = vsrc[(size_t)(16 * s2 + j) * Dk];
    }

    // B) issue K(t+1) loads (cooperative: wave's 8 rows, 4KB)
    float4 kr0, kr1, kr2, kr3;
    if (t + 1 < NT) {
      const float* src = Kb + (size_t)(kb + KT + krow_l) * Dk + kcol0;
      kr0 = *(const float4*)(src);
      kr1 = *(const float4*)(src + 4);
      kr2 = *(const float4*)(src + 8);
      kr3 = *(const float4*)(src + 12);
    }
    __builtin_amdgcn_sched_barrier(0);  // keep load issues above compute

    // C) K fragments from LDS buf[t&1] (swizzled, conflict-free b128)
    const char* kbase = kls + (t & 1) * 8192;
    bf16x8 kf[8];
#pragma unroll
    for (int s = 0; s < 8; ++s) {
      const int o = (c32 * 256 + hi * 16 + s * 32) ^ ((c32 & 7) << 4);
      kf[s] = *(const bf16x8*)(kbase + o);
    }

    // D) S^T[key,q] = mfma(A=K, B=Q): lane q=c32, regs = keys crow(r,hi)
    f32x16 S;
#pragma unroll
    for (int r = 0; r < 16; ++r) S[r] = 0.0f;
#pragma unroll
    for (int s = 0; s < 8; ++s)
      S = __builtin_amdgcn_mfma_f32_32x32x16_bf16(kf[s], qa[s], S, 0, 0, 0);

    // E) online softmax, in-register (per-lane q; 16 keys/lane + xhalf)
    float tmax = S[0];
#pragma unroll
    for (int r = 1; r < 16; ++r) tmax = fmaxf(tmax, S[r]);
    tmax = fmaxf(tmax, __shfl_xor(tmax, 32, 64));
    const float mn = fmaxf(m_r, tmax);
    const float sf = __expf(m_r - mn);
    m_r = mn;
    float p[16];
#pragma unroll
    for (int r = 0; r < 16; ++r) p[r] = __expf(S[r] - mn);
    float rs = p[0];
#pragma unroll
    for (int r = 1; r < 16; ++r) rs += p[r];
    rs += __shfl_xor(rs, 32, 64);
    l_r = l_r * sf + rs;
#pragma unroll
    for (int r = 0; r < 16; ++r) acc[r] *= sf;

    // F) P^T -> B-fragments via cvt_pk + permlane32_swap
    unsigned a0 = cvt_pk(p[0], p[1]),   a1 = cvt_pk(p[2], p[3]);
    unsigned a2 = cvt_pk(p[4], p[5]),   a3 = cvt_pk(p[6], p[7]);
    unsigned a4 = cvt_pk(p[8], p[9]),   a5 = cvt_pk(p[10], p[11]);
    unsigned a6 = cvt_pk(p[12], p[13]), a7 = cvt_pk(p[14], p[15]);
    plane32_swap(a0, a2);
    plane32_swap(a1, a3);
    plane32_swap(a4, a6);
    plane32_swap(a5, a7);
    frag_u pa0, pa1;
    pa0.u[0] = a0; pa0.u[1] = a1; pa0.u[2] = a2; pa0.u[3] = a3;
    pa1.u[0] = a4; pa1.u[1] = a5; pa1.u[2] = a6; pa1.u[3] = a7;

    // G) V fragments from the prefetched regs; O^T += mfma(A=V^T, B=P^T)
    frag_u vf0, vf1;
    vf0.u[0] = cvt_pk(vr[0], vr[1]);   vf0.u[1] = cvt_pk(vr[2], vr[3]);
    vf0.u[2] = cvt_pk(vr[4], vr[5]);   vf0.u[3] = cvt_pk(vr[6], vr[7]);
    vf1.u[0] = cvt_pk(vr[8], vr[9]);   vf1.u[1] = cvt_pk(vr[10], vr[11]);
    vf1.u[2] = cvt_pk(vr[12], vr[13]); vf1.u[3] = cvt_pk(vr[14], vr[15]);
    acc = __builtin_amdgcn_mfma_f32_32x32x16_bf16(vf0.v, pa0.v, acc, 0, 0, 0);
    acc = __builtin_amdgcn_mfma_f32_32x32x16_bf16(vf1.v, pa1.v, acc, 0, 0, 0);

    // H) stage K(t+1) into buf[(t+1)&1] (loads had the whole compute window)
    if (t + 1 < NT) {
      frag_u lo, hi4;
      lo.u[0] = cvt_pk(kr0.x, kr0.y);  lo.u[1] = cvt_pk(kr0.z, kr0.w);
      lo.u[2] = cvt_pk(kr1.x, kr1.y);  lo.u[3] = cvt_pk(kr1.z, kr1.w);
      hi4.u[0] = cvt_pk(kr2.x, kr2.y); hi4.u[1] = cvt_pk(kr2.z, kr2.w);
      hi4.u[2] = cvt_pk(kr3.x, kr3.y); hi4.u[3] = cvt_pk(kr3.z, kr3.w);
      char* wbase = kls + ((t + 1) & 1) * 8192;
      *(bf16x8*)(wbase + (ko0 ^ ksw)) = lo.v;
      *(bf16x8*)(wbase + ((ko0 + 16) ^ ksw)) = hi4.v;
    }
    __syncthreads();
  }

  // ---- epilogue: O^T -> smem transpose -> coalesced partial store
  float* ol = smem;  // [128][33]
#pragma unroll
  for (int r = 0; r < 16; ++r) {
    const int vv = 32 * w + (r & 3) + 8 * (r >> 2) + 4 * hi;
    ol[vv * 33 + c32] = acc[r];
  }
  __syncthreads();
  {
    float* oo = ows + (size_t)wg * 4096;
    const int q = tid >> 3;
    const int v0 = (tid & 7) * 16;
#pragma unroll
    for (int g = 0; g < 4; ++g) {
      float4 s;
      s.x = ol[(v0 + 4 * g + 0) * 33 + q];
      s.y = ol[(v0 + 4 * g + 1) * 33 + q];
      s.z = ol[(v0 + 4 * g + 2) * 33 + q];
      s.w = ol[(v0 + 4 * g + 3) * 33 + q];
      *(float4*)(oo + q * 128 + v0 + 4 * g) = s;
    }
  }
  if (w == 0 && hi == 0) {
    mws[wg * 32 + c32] = m_r;
    lws[wg * 32 + c32] = l_r;
  }
}

// Combine NSPLIT partials per (b, q) row.
__global__ void attn_combine(const float* __restrict__ ows,
                             const float* __restrict__ mws,
                             const float* __restrict__ lws,
                             float* __restrict__ out) {
  const int bq = blockIdx.x;       // b*32 + q
  const int v = threadIdx.x;       // 0..127
  const int b = bq >> 5;
  const int qrow = bq & 31;
  const int slot0 = b * NSPLIT;

  float M = -1e30f;
#pragma unroll
  for (int c = 0; c < NSPLIT; ++c)
    M = fmaxf(M, mws[(slot0 + c) * 32 + qrow]);

  float acc = 0.0f, L = 0.0f;
#pragma unroll
  for (int c = 0; c < NSPLIT; ++c) {
    const float f = __expf(mws[(slot0 + c) * 32 + qrow] - M);
    L += lws[(slot0 + c) * 32 + qrow] * f;
    acc += f * ows[(size_t)(slot0 + c) * 4096 + qrow * 128 + v];
  }
  out[(size_t)bq * 128 + v] = acc / L;
}

extern "C" void kernel_launch(void* const* d_in, const int* in_sizes, int n_in,
                              void* d_out, int out_size, void* d_ws, size_t ws_size,
                              hipStream_t stream) {
  const float* Q = (const float*)d_in[0];
  const float* K = (const float*)d_in[1];
  const float* V = (const float*)d_in[2];
  float* out = (float*)d_out;

  float* ows = (float*)d_ws;                        // 512 * 4096 f32 = 8 MB
  float* mws = ows + (size_t)32 * NSPLIT * 4096;    // 512 * 32 f32
  float* lws = mws + (size_t)32 * NSPLIT * 32;      // 512 * 32 f32

  attn_partial<<<32 * NSPLIT, 256, 0, stream>>>(Q, K, V, ows, mws, lws);
  attn_combine<<<32 * 32, 128, 0, stream>>>(ows, mws, lws, out);
}